// Round 1
// baseline (292.291 us; speedup 1.0000x reference)
//
#include <hip/hip_runtime.h>
#include <cfloat>

// Problem constants (from reference): M=N=64, DIM=512, B=4096, SIGMA=32
#define DIMK 512
#define MN   4096
#define BATCH 4096

// GEMM tiling
#define BM 128
#define BN 128
#define BK 32
#define STRD (BM + 4)          // LDS row stride (floats), keeps 16B alignment + bank shift
#define NTILES (MN / BN)       // 32 column tiles

// ---------------------------------------------------------------------------
// Kernel 1: w2[k] = sum_d W[k][d]^2   (one wave per row)
// ---------------------------------------------------------------------------
__global__ __launch_bounds__(256) void w2_kernel(const float* __restrict__ W,
                                                 float* __restrict__ w2) {
    int wave = threadIdx.x >> 6;
    int lane = threadIdx.x & 63;
    int row  = blockIdx.x * 4 + wave;
    const float* wr = W + (size_t)row * DIMK + lane * 8;
    float4 a = *(const float4*)wr;
    float4 b = *(const float4*)(wr + 4);
    float s = a.x*a.x + a.y*a.y + a.z*a.z + a.w*a.w
            + b.x*b.x + b.y*b.y + b.z*b.z + b.w*b.w;
#pragma unroll
    for (int o = 32; o > 0; o >>= 1) s += __shfl_down(s, o);
    if (lane == 0) w2[row] = s;
}

// ---------------------------------------------------------------------------
// Kernel 2: tiled fp32 GEMM  s[b,k] = w2[k] - 2*dot(X[b], W[k])
// with per-(row, n-tile) argmin partials written to workspace.
// grid = (MN/BN, BATCH/BM), block = 256 (16x16 threads, 8x8 microtile)
// ---------------------------------------------------------------------------
__global__ __launch_bounds__(256, 4) void score_kernel(
        const float* __restrict__ X, const float* __restrict__ W,
        const float* __restrict__ w2,
        float* __restrict__ pval, int* __restrict__ pidx) {
    __shared__ float lds[2 * BK * STRD];   // As + Bs, K-major, 33792 B
    float* As = lds;
    float* Bs = lds + BK * STRD;

    const int t  = threadIdx.x;
    const int tx = t & 15;
    const int ty = t >> 4;
    const int m0 = blockIdx.y * BM;
    const int n0 = blockIdx.x * BN;
    const float* Xb = X + (size_t)m0 * DIMK;
    const float* Wb = W + (size_t)n0 * DIMK;

    float acc[8][8];
#pragma unroll
    for (int i = 0; i < 8; i++)
#pragma unroll
        for (int j = 0; j < 8; j++) acc[i][j] = 0.0f;

    for (int k0 = 0; k0 < DIMK; k0 += BK) {
        __syncthreads();
        // stage A and B tiles (128 rows x 32 k) into LDS, K-major
#pragma unroll
        for (int q = 0; q < 4; q++) {
            int f   = t + 256 * q;        // float4 id in tile, 0..1023
            int row = f >> 3;             // 8 float4 per row of 32 floats
            int c4  = (f & 7) * 4;
            float4 av = *(const float4*)(Xb + (size_t)row * DIMK + k0 + c4);
            As[(c4 + 0) * STRD + row] = av.x;
            As[(c4 + 1) * STRD + row] = av.y;
            As[(c4 + 2) * STRD + row] = av.z;
            As[(c4 + 3) * STRD + row] = av.w;
            float4 bv = *(const float4*)(Wb + (size_t)row * DIMK + k0 + c4);
            Bs[(c4 + 0) * STRD + row] = bv.x;
            Bs[(c4 + 1) * STRD + row] = bv.y;
            Bs[(c4 + 2) * STRD + row] = bv.z;
            Bs[(c4 + 3) * STRD + row] = bv.w;
        }
        __syncthreads();

#pragma unroll 8
        for (int kk = 0; kk < BK; kk++) {
            const float* Ak = As + kk * STRD;
            const float* Bk = Bs + kk * STRD;
            float4 a0 = *(const float4*)(Ak + ty * 4);
            float4 a1 = *(const float4*)(Ak + 64 + ty * 4);
            float4 b0 = *(const float4*)(Bk + tx * 4);
            float4 b1 = *(const float4*)(Bk + 64 + tx * 4);
            float av[8] = {a0.x, a0.y, a0.z, a0.w, a1.x, a1.y, a1.z, a1.w};
            float bv[8] = {b0.x, b0.y, b0.z, b0.w, b1.x, b1.y, b1.z, b1.w};
#pragma unroll
            for (int i = 0; i < 8; i++)
#pragma unroll
                for (int j = 0; j < 8; j++)
                    acc[i][j] += av[i] * bv[j];
        }
    }

    // -------- epilogue: scores + argmin within this 128x128 tile --------
    __syncthreads();                        // done with As/Bs; reuse as scratch
    float* red_v = lds;                     // [BM][17]
    int*   red_i = (int*)(lds + BM * 17);   // [BM][17]

    float w2c[8];
    int   ncol[8];
#pragma unroll
    for (int j = 0; j < 8; j++) {
        int nl  = (j < 4) ? (tx * 4 + j) : (64 + tx * 4 + (j - 4));
        ncol[j] = n0 + nl;
        w2c[j]  = w2[n0 + nl];
    }
#pragma unroll
    for (int i = 0; i < 8; i++) {
        int ml = (i < 4) ? (ty * 4 + i) : (64 + ty * 4 + (i - 4));
        float bvv = FLT_MAX;
        int   bii = 0x7FFFFFFF;
#pragma unroll
        for (int j = 0; j < 8; j++) {
            float v = w2c[j] - 2.0f * acc[i][j];
            if (v < bvv || (v == bvv && ncol[j] < bii)) { bvv = v; bii = ncol[j]; }
        }
        red_v[ml * 17 + tx] = bvv;
        red_i[ml * 17 + tx] = bii;
    }
    __syncthreads();
    if (t < BM) {
        float bvv = FLT_MAX;
        int   bii = 0x7FFFFFFF;
#pragma unroll
        for (int x = 0; x < 16; x++) {
            float v  = red_v[t * 17 + x];
            int   ii = red_i[t * 17 + x];
            if (v < bvv || (v == bvv && ii < bii)) { bvv = v; bii = ii; }
        }
        pval[(size_t)(m0 + t) * NTILES + blockIdx.x] = bvv;
        pidx[(size_t)(m0 + t) * NTILES + blockIdx.x] = bii;
    }
}

// ---------------------------------------------------------------------------
// Kernel 3: per batch row — reduce partials to BMU, build separable Gaussian
// tables, write 4096 outputs. grid = BATCH, block = 256.
// ---------------------------------------------------------------------------
__global__ __launch_bounds__(256) void epilogue_kernel(
        const float* __restrict__ pval, const int* __restrict__ pidx,
        const int* __restrict__ decay_p, const int* __restrict__ it_p,
        float* __restrict__ out) {
    __shared__ float er[64];
    __shared__ float ec[64];
    __shared__ int   s_idx;
    const int b = blockIdx.x;
    const int t = threadIdx.x;

    if (t < 64) {
        float v  = FLT_MAX;
        int   ii = 0x7FFFFFFF;
        if (t < NTILES) {
            v  = pval[(size_t)b * NTILES + t];
            ii = pidx[(size_t)b * NTILES + t];
        }
#pragma unroll
        for (int o = 16; o > 0; o >>= 1) {
            float ov = __shfl_down(v, o);
            int   oi = __shfl_down(ii, o);
            if (ov < v || (ov == v && oi < ii)) { v = ov; ii = oi; }
        }
        if (t == 0) s_idx = ii;
    }
    __syncthreads();
    const int r = s_idx >> 6;
    const int c = s_idx & 63;
    const float lr  = expf(-(float)(*it_p) / (float)(*decay_p));
    const float so  = 32.0f * lr;          // SIGMA = max(64,64)/2 = 32
    const float inv = 1.0f / (so * so);
    if (t < 64) {
        float d = (float)(t - r);
        er[t] = expf(-d * d * inv);
    } else if (t < 128) {
        int j = t - 64;
        float d = (float)(j - c);
        ec[j] = expf(-d * d * inv);
    }
    __syncthreads();
    float4* out4 = (float4*)(out + (size_t)b * 4096);
#pragma unroll
    for (int q = 0; q < 4; q++) {
        int f  = t + 256 * q;       // float4 index within the row
        int i  = f >> 4;            // element 4f -> grid row (4f)>>6
        int j0 = (f & 15) * 4;      // grid col of first element
        float e = er[i];
        out4[f] = make_float4(e * ec[j0], e * ec[j0 + 1],
                              e * ec[j0 + 2], e * ec[j0 + 3]);
    }
}

// ---------------------------------------------------------------------------
extern "C" void kernel_launch(void* const* d_in, const int* in_sizes, int n_in,
                              void* d_out, int out_size, void* d_ws, size_t ws_size,
                              hipStream_t stream) {
    const float* X       = (const float*)d_in[0];   // batch   [4096,512]
    const float* W       = (const float*)d_in[1];   // weights [4096,512]
    // d_in[2] = locations: deterministic (k/64, k%64) grid — computed inline
    const int*   decay_p = (const int*)d_in[3];
    const int*   it_p    = (const int*)d_in[4];
    float* out = (float*)d_out;

    // workspace: w2 (16KB) | pval (512KB) | pidx (512KB)
    float* w2   = (float*)d_ws;
    float* pval = w2 + MN;
    int*   pidx = (int*)(pval + (size_t)BATCH * NTILES);

    w2_kernel<<<MN / 4, 256, 0, stream>>>(W, w2);
    dim3 g2(MN / BN, BATCH / BM);
    score_kernel<<<g2, 256, 0, stream>>>(X, W, w2, pval, pidx);
    epilogue_kernel<<<BATCH, 256, 0, stream>>>(pval, pidx, decay_p, it_p, out);
}

// Round 2
// 180.785 us; speedup vs baseline: 1.6168x; 1.6168x over previous
//
#include <hip/hip_runtime.h>
#include <cfloat>

// Problem constants: M=N=64 grid, DIM=512, B=4096, SIGMA=32
#define DIMK 512
#define MN   4096
#define BATCH 4096
#define BK 32
#define NCHUNK 64   // per-row argmin partials: 64 chunks of 64 cols

typedef _Float16 half8_t __attribute__((ext_vector_type(8)));
typedef _Float16 half4_t __attribute__((ext_vector_type(4)));
typedef float f32x4 __attribute__((ext_vector_type(4)));

// async global->LDS, 16B per lane; LDS dest is wave-uniform base + lane*16
#define GLD16(gp, lp) __builtin_amdgcn_global_load_lds( \
    (const __attribute__((address_space(1))) void*)(gp), \
    (__attribute__((address_space(3))) void*)(lp), 16, 0, 0)

// ---------------------------------------------------------------------------
// fp32 -> (hi, mid) f16 split: a = hi + mid + O(2^-22 |a|)
// ---------------------------------------------------------------------------
__global__ __launch_bounds__(256) void convert_kernel(
        const float* __restrict__ src,
        _Float16* __restrict__ hi, _Float16* __restrict__ mid) {
    size_t idx = ((size_t)blockIdx.x * 256 + threadIdx.x) * 4;
    float4 v = *(const float4*)(src + idx);
    _Float16 h0 = (_Float16)v.x, h1 = (_Float16)v.y,
             h2 = (_Float16)v.z, h3 = (_Float16)v.w;
    half4_t hv = {h0, h1, h2, h3};
    half4_t mv = {(_Float16)(v.x - (float)h0), (_Float16)(v.y - (float)h1),
                  (_Float16)(v.z - (float)h2), (_Float16)(v.w - (float)h3)};
    *(half4_t*)(hi + idx) = hv;
    *(half4_t*)(mid + idx) = mv;
}

// ---------------------------------------------------------------------------
// w2[k] = sum_d W[k][d]^2  (fp32 exact, one wave per row)
// ---------------------------------------------------------------------------
__global__ __launch_bounds__(256) void w2_kernel(const float* __restrict__ W,
                                                 float* __restrict__ w2) {
    int wave = threadIdx.x >> 6;
    int lane = threadIdx.x & 63;
    int row  = blockIdx.x * 4 + wave;
    const float* wr = W + (size_t)row * DIMK + lane * 8;
    float4 a = *(const float4*)wr;
    float4 b = *(const float4*)(wr + 4);
    float s = a.x*a.x + a.y*a.y + a.z*a.z + a.w*a.w
            + b.x*b.x + b.y*b.y + b.z*b.z + b.w*b.w;
#pragma unroll
    for (int o = 32; o > 0; o >>= 1) s += __shfl_down(s, o);
    if (lane == 0) w2[row] = s;
}

// ---------------------------------------------------------------------------
// MFMA score kernel: s[b,k] = w2[k] - 2*dot(X[b],W[k]) via 3-product f16 split.
// 128x128 tile, BK=32, 4 waves each computing a 64x64 region (4x4 MFMA tiles).
// LDS blocks are lane-swizzled (16 rows x 4 k-octets) so fragment reads are
// linear in lane (conflict-free) and match global_load_lds deposit order.
// ---------------------------------------------------------------------------
__global__ __launch_bounds__(256, 2) void score_kernel(
        const _Float16* __restrict__ Xhi, const _Float16* __restrict__ Xmi,
        const _Float16* __restrict__ Whi, const _Float16* __restrict__ Wmi,
        const float* __restrict__ w2,
        float* __restrict__ pval, int* __restrict__ pidx) {
    __shared__ __align__(16) _Float16 lds[16384];   // 32 KB: Ah|Am|Bh|Bm (8KB each)
    _Float16* sAh = lds;
    _Float16* sAm = lds + 4096;
    _Float16* sBh = lds + 8192;
    _Float16* sBm = lds + 12288;

    const int t    = threadIdx.x;
    const int lane = t & 63;
    const int w    = t >> 6;        // wave 0..3
    const int wm   = w >> 1;        // wave m-half
    const int wn   = w & 1;         // wave n-half
    const int m0   = blockIdx.y * 128;
    const int n0   = blockIdx.x * 128;

    f32x4 acc[4][4];
#pragma unroll
    for (int i = 0; i < 4; i++)
#pragma unroll
        for (int j = 0; j < 4; j++) acc[i][j] = (f32x4){0.f, 0.f, 0.f, 0.f};

    // staging: wave w loads blocks (2w, 2w+1) of each of the 4 arrays.
    // within a 1KB block: lane l -> row (l&15), k-octet (l>>4).
    const int r16 = lane & 15;
    const int kg  = lane >> 4;
    const int b0  = 2 * w, b1 = 2 * w + 1;
    const size_t ko = (size_t)kg * 8;
    const _Float16* gAh0 = Xhi + (size_t)(m0 + b0 * 16 + r16) * DIMK + ko;
    const _Float16* gAh1 = Xhi + (size_t)(m0 + b1 * 16 + r16) * DIMK + ko;
    const _Float16* gAm0 = Xmi + (size_t)(m0 + b0 * 16 + r16) * DIMK + ko;
    const _Float16* gAm1 = Xmi + (size_t)(m0 + b1 * 16 + r16) * DIMK + ko;
    const _Float16* gBh0 = Whi + (size_t)(n0 + b0 * 16 + r16) * DIMK + ko;
    const _Float16* gBh1 = Whi + (size_t)(n0 + b1 * 16 + r16) * DIMK + ko;
    const _Float16* gBm0 = Wmi + (size_t)(n0 + b0 * 16 + r16) * DIMK + ko;
    const _Float16* gBm1 = Wmi + (size_t)(n0 + b1 * 16 + r16) * DIMK + ko;
    _Float16* dAh0 = sAh + b0 * 512;  _Float16* dAh1 = sAh + b1 * 512;
    _Float16* dAm0 = sAm + b0 * 512;  _Float16* dAm1 = sAm + b1 * 512;
    _Float16* dBh0 = sBh + b0 * 512;  _Float16* dBh1 = sBh + b1 * 512;
    _Float16* dBm0 = sBm + b0 * 512;  _Float16* dBm1 = sBm + b1 * 512;

    for (int k0 = 0; k0 < DIMK; k0 += BK) {
        __syncthreads();                 // previous iter's frag reads complete
        GLD16(gAh0 + k0, dAh0);
        GLD16(gAh1 + k0, dAh1);
        GLD16(gAm0 + k0, dAm0);
        GLD16(gAm1 + k0, dAm1);
        GLD16(gBh0 + k0, dBh0);
        GLD16(gBh1 + k0, dBh1);
        GLD16(gBm0 + k0, dBm0);
        GLD16(gBm1 + k0, dBm1);
        __syncthreads();                 // drains vmcnt (global_load_lds)

        half8_t ah[4], am[4], bh[4], bm[4];
#pragma unroll
        for (int i = 0; i < 4; i++) {
            ah[i] = *(const half8_t*)(sAh + (wm * 4 + i) * 512 + lane * 8);
            am[i] = *(const half8_t*)(sAm + (wm * 4 + i) * 512 + lane * 8);
            bh[i] = *(const half8_t*)(sBh + (wn * 4 + i) * 512 + lane * 8);
            bm[i] = *(const half8_t*)(sBm + (wn * 4 + i) * 512 + lane * 8);
        }
#pragma unroll
        for (int i = 0; i < 4; i++)
#pragma unroll
            for (int j = 0; j < 4; j++) {
                acc[i][j] = __builtin_amdgcn_mfma_f32_16x16x32_f16(am[i], bh[j], acc[i][j], 0, 0, 0);
                acc[i][j] = __builtin_amdgcn_mfma_f32_16x16x32_f16(ah[i], bm[j], acc[i][j], 0, 0, 0);
                acc[i][j] = __builtin_amdgcn_mfma_f32_16x16x32_f16(ah[i], bh[j], acc[i][j], 0, 0, 0);
            }
    }

    // ---- epilogue: per-row argmin over this wave's 64 cols ----
    // D layout: col = lane&15, row = (lane>>4)*4 + v   (m89/m91 verified)
    const int q  = lane >> 4;
    const int cl = lane & 15;
    float w2v[4];
    int   ncol[4];
#pragma unroll
    for (int j = 0; j < 4; j++) {
        ncol[j] = n0 + wn * 64 + j * 16 + cl;
        w2v[j]  = w2[ncol[j]];
    }
#pragma unroll
    for (int i = 0; i < 4; i++)
#pragma unroll
        for (int v = 0; v < 4; v++) {
            float bv = FLT_MAX;
            int   bi = 0x7FFFFFFF;
#pragma unroll
            for (int j = 0; j < 4; j++) {        // j ascending -> ties keep lower n
                float s = w2v[j] - 2.0f * acc[i][j][v];
                if (s < bv) { bv = s; bi = ncol[j]; }
            }
#pragma unroll
            for (int mask = 1; mask <= 8; mask <<= 1) {   // reduce over 16 col-lanes
                float ov = __shfl_xor(bv, mask);
                int   oi = __shfl_xor(bi, mask);
                if (ov < bv || (ov == bv && oi < bi)) { bv = ov; bi = oi; }
            }
            if (cl == 0) {
                int m = m0 + wm * 64 + i * 16 + q * 4 + v;
                int chunk = blockIdx.x * 2 + wn;
                pval[(size_t)m * NCHUNK + chunk] = bv;
                pidx[(size_t)m * NCHUNK + chunk] = bi;
            }
        }
}

// ---------------------------------------------------------------------------
// Final: reduce 64 partials/row -> BMU, separable Gaussian, write 4096 floats.
// ---------------------------------------------------------------------------
__global__ __launch_bounds__(256) void epilogue_kernel(
        const float* __restrict__ pval, const int* __restrict__ pidx,
        const int* __restrict__ decay_p, const int* __restrict__ it_p,
        float* __restrict__ out) {
    __shared__ float er[64];
    __shared__ float ec[64];
    __shared__ int   s_idx;
    const int b = blockIdx.x;
    const int t = threadIdx.x;

    if (t < 64) {
        float v  = pval[(size_t)b * NCHUNK + t];
        int   ii = pidx[(size_t)b * NCHUNK + t];
#pragma unroll
        for (int mask = 1; mask <= 32; mask <<= 1) {
            float ov = __shfl_xor(v, mask);
            int   oi = __shfl_xor(ii, mask);
            if (ov < v || (ov == v && oi < ii)) { v = ov; ii = oi; }
        }
        if (t == 0) s_idx = ii;
    }
    __syncthreads();
    const int r = s_idx >> 6;
    const int c = s_idx & 63;
    const float lr  = expf(-(float)(*it_p) / (float)(*decay_p));
    const float so  = 32.0f * lr;          // SIGMA = 32
    const float inv = 1.0f / (so * so);
    if (t < 64) {
        float d = (float)(t - r);
        er[t] = expf(-d * d * inv);
    } else if (t < 128) {
        int j = t - 64;
        float d = (float)(j - c);
        ec[j] = expf(-d * d * inv);
    }
    __syncthreads();
    float4* out4 = (float4*)(out + (size_t)b * 4096);
#pragma unroll
    for (int qq = 0; qq < 4; qq++) {
        int f  = t + 256 * qq;
        int i  = f >> 4;
        int j0 = (f & 15) * 4;
        float e = er[i];
        out4[f] = make_float4(e * ec[j0], e * ec[j0 + 1],
                              e * ec[j0 + 2], e * ec[j0 + 3]);
    }
}

// ---------------------------------------------------------------------------
extern "C" void kernel_launch(void* const* d_in, const int* in_sizes, int n_in,
                              void* d_out, int out_size, void* d_ws, size_t ws_size,
                              hipStream_t stream) {
    const float* X       = (const float*)d_in[0];   // [4096,512]
    const float* W       = (const float*)d_in[1];   // [4096,512]
    const int*   decay_p = (const int*)d_in[3];
    const int*   it_p    = (const int*)d_in[4];
    float* out = (float*)d_out;

    // ws: Xhi|Xmi|Whi|Wmi (4MB each f16) | w2 16KB | pval 1MB | pidx 1MB
    _Float16* Xhi = (_Float16*)d_ws;
    _Float16* Xmi = Xhi + (size_t)BATCH * DIMK;
    _Float16* Whi = Xmi + (size_t)BATCH * DIMK;
    _Float16* Wmi = Whi + (size_t)MN * DIMK;
    float*    w2  = (float*)(Wmi + (size_t)MN * DIMK);
    float*    pval = w2 + MN;
    int*      pidx = (int*)(pval + (size_t)BATCH * NCHUNK);

    convert_kernel<<<2048, 256, 0, stream>>>(X, Xhi, Xmi);
    convert_kernel<<<2048, 256, 0, stream>>>(W, Whi, Wmi);
    w2_kernel<<<MN / 4, 256, 0, stream>>>(W, w2);
    score_kernel<<<dim3(32, 32), 256, 0, stream>>>(Xhi, Xmi, Whi, Wmi, w2, pval, pidx);
    epilogue_kernel<<<BATCH, 256, 0, stream>>>(pval, pidx, decay_p, it_p, out);
}

// Round 3
// 174.995 us; speedup vs baseline: 1.6703x; 1.0331x over previous
//
#include <hip/hip_runtime.h>
#include <cfloat>

// Problem constants: M=N=64 grid, DIM=512, B=4096, SIGMA=32
#define DIMK 512
#define MN   4096
#define BATCH 4096
#define BK 32
#define NCHUNK 64   // per-row argmin partials: 64 chunks of 64 cols

typedef _Float16 half8_t __attribute__((ext_vector_type(8)));
typedef _Float16 half4_t __attribute__((ext_vector_type(4)));
typedef float f32x4 __attribute__((ext_vector_type(4)));

// async global->LDS, 16B per lane; LDS dest is wave-uniform base + lane*16
#define GLD16(gp, lp) __builtin_amdgcn_global_load_lds( \
    (const __attribute__((address_space(1))) void*)(gp), \
    (__attribute__((address_space(3))) void*)(lp), 16, 0, 0)

// ---------------------------------------------------------------------------
// fp32 -> (hi, mid) f16 split: a = hi + mid + O(2^-22 |a|)
// one launch handles both X (blocks < 2048) and W (blocks >= 2048)
// ---------------------------------------------------------------------------
__global__ __launch_bounds__(256) void convert_kernel(
        const float* __restrict__ X, const float* __restrict__ W,
        _Float16* __restrict__ Xhi, _Float16* __restrict__ Xmi,
        _Float16* __restrict__ Whi, _Float16* __restrict__ Wmi) {
    int blk = blockIdx.x;
    const float* src;
    _Float16 *hi, *mid;
    size_t base;
    if (blk < 2048) {
        src = X; hi = Xhi; mid = Xmi;
        base = (size_t)blk * 1024;
    } else {
        src = W; hi = Whi; mid = Wmi;
        base = (size_t)(blk - 2048) * 1024;
    }
    size_t idx = base + (size_t)threadIdx.x * 4;
    float4 v = *(const float4*)(src + idx);
    _Float16 h0 = (_Float16)v.x, h1 = (_Float16)v.y,
             h2 = (_Float16)v.z, h3 = (_Float16)v.w;
    half4_t hv = {h0, h1, h2, h3};
    half4_t mv = {(_Float16)(v.x - (float)h0), (_Float16)(v.y - (float)h1),
                  (_Float16)(v.z - (float)h2), (_Float16)(v.w - (float)h3)};
    *(half4_t*)(hi + idx) = hv;
    *(half4_t*)(mid + idx) = mv;
}

// ---------------------------------------------------------------------------
// w2[k] = sum_d W[k][d]^2  (fp32 exact, one wave per row)
// ---------------------------------------------------------------------------
__global__ __launch_bounds__(256) void w2_kernel(const float* __restrict__ W,
                                                 float* __restrict__ w2) {
    int wave = threadIdx.x >> 6;
    int lane = threadIdx.x & 63;
    int row  = blockIdx.x * 4 + wave;
    const float* wr = W + (size_t)row * DIMK + lane * 8;
    float4 a = *(const float4*)wr;
    float4 b = *(const float4*)(wr + 4);
    float s = a.x*a.x + a.y*a.y + a.z*a.z + a.w*a.w
            + b.x*b.x + b.y*b.y + b.z*b.z + b.w*b.w;
#pragma unroll
    for (int o = 32; o > 0; o >>= 1) s += __shfl_down(s, o);
    if (lane == 0) w2[row] = s;
}

// ---------------------------------------------------------------------------
// MFMA score kernel: s[b,k] = w2[k] - 2*dot(X[b],W[k]) via 3-product f16 split.
// 128x128 tile, BK=32, double-buffered LDS (64KB), ONE barrier per K-iter:
// prefetch tile k+1 into the alternate buffer immediately after the barrier,
// then compute on tile k — the vmcnt drain at the next barrier finds the
// prefetch already complete (issued a full MFMA phase earlier).
// ---------------------------------------------------------------------------
__global__ __launch_bounds__(256, 2) void score_kernel(
        const _Float16* __restrict__ Xhi, const _Float16* __restrict__ Xmi,
        const _Float16* __restrict__ Whi, const _Float16* __restrict__ Wmi,
        const float* __restrict__ w2,
        float* __restrict__ pval, int* __restrict__ pidx) {
    // 64 KB: two buffers, each Ah|Am|Bh|Bm (4096 f16 = 8KB each)
    __shared__ __align__(16) _Float16 lds[2][16384];

    const int t    = threadIdx.x;
    const int lane = t & 63;
    const int w    = t >> 6;        // wave 0..3
    const int wm   = w >> 1;        // wave m-half
    const int wn   = w & 1;         // wave n-half
    const int m0   = blockIdx.y * 128;
    const int n0   = blockIdx.x * 128;

    f32x4 acc[4][4];
#pragma unroll
    for (int i = 0; i < 4; i++)
#pragma unroll
        for (int j = 0; j < 4; j++) acc[i][j] = (f32x4){0.f, 0.f, 0.f, 0.f};

    // staging: wave w loads 16-row blocks (2w, 2w+1) of each of the 4 arrays.
    // within a 1KB block: lane l -> row (l&15), k-octet (l>>4).
    const int r16 = lane & 15;
    const int kg  = lane >> 4;
    const int b0  = 2 * w, b1 = 2 * w + 1;
    const size_t ko = (size_t)kg * 8;
    const _Float16* gA[4];
    const _Float16* gB[4];
    gA[0] = Xhi + (size_t)(m0 + b0 * 16 + r16) * DIMK + ko;
    gA[1] = Xhi + (size_t)(m0 + b1 * 16 + r16) * DIMK + ko;
    gA[2] = Xmi + (size_t)(m0 + b0 * 16 + r16) * DIMK + ko;
    gA[3] = Xmi + (size_t)(m0 + b1 * 16 + r16) * DIMK + ko;
    gB[0] = Whi + (size_t)(n0 + b0 * 16 + r16) * DIMK + ko;
    gB[1] = Whi + (size_t)(n0 + b1 * 16 + r16) * DIMK + ko;
    gB[2] = Wmi + (size_t)(n0 + b0 * 16 + r16) * DIMK + ko;
    gB[3] = Wmi + (size_t)(n0 + b1 * 16 + r16) * DIMK + ko;
    // LDS dest offsets (f16 units) within a buffer: Ah@0 Am@4096 Bh@8192 Bm@12288
    const int dA[4] = {b0 * 512, b1 * 512, 4096 + b0 * 512, 4096 + b1 * 512};
    const int dB[4] = {8192 + b0 * 512, 8192 + b1 * 512,
                       12288 + b0 * 512, 12288 + b1 * 512};

    // prologue: fill buffer 0 with tile k=0
#pragma unroll
    for (int p = 0; p < 4; p++) {
        GLD16(gA[p], &lds[0][dA[p]]);
        GLD16(gB[p], &lds[0][dB[p]]);
    }

    int cur = 0;
    for (int k0 = 0; k0 < DIMK; k0 += BK) {
        __syncthreads();               // lds[cur] staged; prior frag reads done
        if (k0 + BK < DIMK) {          // prefetch next tile into alternate buf
            int nk = k0 + BK;
#pragma unroll
            for (int p = 0; p < 4; p++) {
                GLD16(gA[p] + nk, &lds[cur ^ 1][dA[p]]);
                GLD16(gB[p] + nk, &lds[cur ^ 1][dB[p]]);
            }
        }
        const _Float16* sAh = &lds[cur][0];
        const _Float16* sAm = &lds[cur][4096];
        const _Float16* sBh = &lds[cur][8192];
        const _Float16* sBm = &lds[cur][12288];

        half8_t ah[4], am[4], bh[4], bm[4];
#pragma unroll
        for (int i = 0; i < 4; i++) {
            ah[i] = *(const half8_t*)(sAh + (wm * 4 + i) * 512 + lane * 8);
            am[i] = *(const half8_t*)(sAm + (wm * 4 + i) * 512 + lane * 8);
            bh[i] = *(const half8_t*)(sBh + (wn * 4 + i) * 512 + lane * 8);
            bm[i] = *(const half8_t*)(sBm + (wn * 4 + i) * 512 + lane * 8);
        }
#pragma unroll
        for (int i = 0; i < 4; i++)
#pragma unroll
            for (int j = 0; j < 4; j++) {
                acc[i][j] = __builtin_amdgcn_mfma_f32_16x16x32_f16(am[i], bh[j], acc[i][j], 0, 0, 0);
                acc[i][j] = __builtin_amdgcn_mfma_f32_16x16x32_f16(ah[i], bm[j], acc[i][j], 0, 0, 0);
                acc[i][j] = __builtin_amdgcn_mfma_f32_16x16x32_f16(ah[i], bh[j], acc[i][j], 0, 0, 0);
            }
        cur ^= 1;
    }

    // ---- epilogue: per-row argmin over this wave's 64 cols ----
    // D layout: col = lane&15, row = (lane>>4)*4 + v   (m89/m91 verified)
    const int q  = lane >> 4;
    const int cl = lane & 15;
    float w2v[4];
    int   ncol[4];
#pragma unroll
    for (int j = 0; j < 4; j++) {
        ncol[j] = n0 + wn * 64 + j * 16 + cl;
        w2v[j]  = w2[ncol[j]];
    }
#pragma unroll
    for (int i = 0; i < 4; i++)
#pragma unroll
        for (int v = 0; v < 4; v++) {
            float bv = FLT_MAX;
            int   bi = 0x7FFFFFFF;
#pragma unroll
            for (int j = 0; j < 4; j++) {        // j ascending -> ties keep lower n
                float s = w2v[j] - 2.0f * acc[i][j][v];
                if (s < bv) { bv = s; bi = ncol[j]; }
            }
#pragma unroll
            for (int mask = 1; mask <= 8; mask <<= 1) {   // reduce over 16 col-lanes
                float ov = __shfl_xor(bv, mask);
                int   oi = __shfl_xor(bi, mask);
                if (ov < bv || (ov == bv && oi < bi)) { bv = ov; bi = oi; }
            }
            if (cl == 0) {
                int m = m0 + wm * 64 + i * 16 + q * 4 + v;
                int chunk = blockIdx.x * 2 + wn;
                pval[(size_t)m * NCHUNK + chunk] = bv;
                pidx[(size_t)m * NCHUNK + chunk] = bi;
            }
        }
}

// ---------------------------------------------------------------------------
// Final: reduce 64 partials/row -> BMU, separable Gaussian, write 4096 floats.
// ---------------------------------------------------------------------------
__global__ __launch_bounds__(256) void epilogue_kernel(
        const float* __restrict__ pval, const int* __restrict__ pidx,
        const int* __restrict__ decay_p, const int* __restrict__ it_p,
        float* __restrict__ out) {
    __shared__ float er[64];
    __shared__ float ec[64];
    __shared__ int   s_idx;
    const int b = blockIdx.x;
    const int t = threadIdx.x;

    if (t < 64) {
        float v  = pval[(size_t)b * NCHUNK + t];
        int   ii = pidx[(size_t)b * NCHUNK + t];
#pragma unroll
        for (int mask = 1; mask <= 32; mask <<= 1) {
            float ov = __shfl_xor(v, mask);
            int   oi = __shfl_xor(ii, mask);
            if (ov < v || (ov == v && oi < ii)) { v = ov; ii = oi; }
        }
        if (t == 0) s_idx = ii;
    }
    __syncthreads();
    const int r = s_idx >> 6;
    const int c = s_idx & 63;
    const float lr  = expf(-(float)(*it_p) / (float)(*decay_p));
    const float so  = 32.0f * lr;          // SIGMA = 32
    const float inv = 1.0f / (so * so);
    if (t < 64) {
        float d = (float)(t - r);
        er[t] = expf(-d * d * inv);
    } else if (t < 128) {
        int j = t - 64;
        float d = (float)(j - c);
        ec[j] = expf(-d * d * inv);
    }
    __syncthreads();
    float4* out4 = (float4*)(out + (size_t)b * 4096);
#pragma unroll
    for (int qq = 0; qq < 4; qq++) {
        int f  = t + 256 * qq;
        int i  = f >> 4;
        int j0 = (f & 15) * 4;
        float e = er[i];
        out4[f] = make_float4(e * ec[j0], e * ec[j0 + 1],
                              e * ec[j0 + 2], e * ec[j0 + 3]);
    }
}

// ---------------------------------------------------------------------------
extern "C" void kernel_launch(void* const* d_in, const int* in_sizes, int n_in,
                              void* d_out, int out_size, void* d_ws, size_t ws_size,
                              hipStream_t stream) {
    const float* X       = (const float*)d_in[0];   // [4096,512]
    const float* W       = (const float*)d_in[1];   // [4096,512]
    const int*   decay_p = (const int*)d_in[3];
    const int*   it_p    = (const int*)d_in[4];
    float* out = (float*)d_out;

    // ws: Xhi|Xmi|Whi|Wmi (4MB each f16) | w2 16KB | pval 1MB | pidx 1MB
    _Float16* Xhi = (_Float16*)d_ws;
    _Float16* Xmi = Xhi + (size_t)BATCH * DIMK;
    _Float16* Whi = Xmi + (size_t)BATCH * DIMK;
    _Float16* Wmi = Whi + (size_t)MN * DIMK;
    float*    w2  = (float*)(Wmi + (size_t)MN * DIMK);
    float*    pval = w2 + MN;
    int*      pidx = (int*)(pval + (size_t)BATCH * NCHUNK);

    convert_kernel<<<4096, 256, 0, stream>>>(X, W, Xhi, Xmi, Whi, Wmi);
    w2_kernel<<<MN / 4, 256, 0, stream>>>(W, w2);
    score_kernel<<<dim3(32, 32), 256, 0, stream>>>(Xhi, Xmi, Whi, Wmi, w2, pval, pidx);
    epilogue_kernel<<<BATCH, 256, 0, stream>>>(pval, pidx, decay_p, it_p, out);
}